// Round 8
// baseline (323.779 us; speedup 1.0000x reference)
//
#include <hip/hip_runtime.h>

#define NN 4
#define CC 20
#define HH 64
#define WW 2048
#define TEAMS 4        // channel teams per block
#define CPT 5          // channels per team
#define BPX 1024       // pixels per block (one row segment)
#define NQ 256         // pixel quads per block
#define HALO 1032      // staged row width: [w0-4, w0+1027]
#define GSTR 21        // gq quad stride (20 + 1 pad)

// R8: merge the 4 channel-group blocks into ONE 1024-thread block and
// deduplicate the Gaussian weights + xyz/mask window reads through LDS
// (registers are the proven spill cliff: R1/R3/R5/R7 all died there).
// Per dy row: stage x/y/z/m halo once (was 4x), compute g once per px
// (was 4x), then every thread runs the R0-proven channel loop (quad =
// tid&255, channels of team tid>>8) with g read from LDS.
// 2 barriers/row: stage->barA->g->barB->channel; next row's LDS writes
// are fenced by the following barA (all threads must pass channel+stage
// first). Register shape stays R0-like: acc 20 + g 20 + sw 12 transient,
// NO window register arrays. Tripwire: WRITE_SIZE must stay 40960 KB.
__global__ __launch_bounds__(1024, 4) void lc_xyz_kernel(
    const float* __restrict__ xyz,
    const float* __restrict__ softmax,
    const int* __restrict__ mask,
    float* __restrict__ out)
{
    __shared__ float ls_x[HALO];
    __shared__ float ls_y[HALO];
    __shared__ float ls_z[HALO];
    __shared__ float ls_m[HALO];          // mask with row/col validity folded in
    __shared__ float gq[NQ * GSTR];       // g[quad][px*5+dx], padded stride 21

    const int tid = (int)threadIdx.x;     // 0..1023
    const int w0  = (int)blockIdx.x * BPX;
    const int h   = (int)blockIdx.y;
    const int n   = (int)blockIdx.z;
    const int hw  = HH * WW;

    const float* xb  = xyz     + (size_t)n * 3  * hw;
    const float* smb = softmax + (size_t)n * CC * hw + (size_t)((tid >> 8) * CPT) * hw;
    const int*   mb  = mask    + (size_t)n * hw;

    // ---- g-phase identity: this thread owns pixel pg = tid ----
    const int pg   = tid;
    const int pcen = w0 + pg;
    const float cx = xb[0 * hw + h * WW + pcen];
    const float cy = xb[1 * hw + h * WW + pcen];
    const float cz = xb[2 * hw + h * WW + pcen];

    // ---- channel-phase identity: quad q, team tid>>8 ----
    const int q   = tid & 255;
    const int p0q = w0 + 4 * q;
    int c0 = p0q - 4; if (c0 < 0) c0 = 0;
    const int c1 = p0q;
    int c2 = p0q + 4; if (c2 > WW - 4) c2 = WW - 4;

    float acc[CPT][4];
#pragma unroll
    for (int c = 0; c < CPT; ++c)
#pragma unroll
        for (int i = 0; i < 4; ++i) acc[c][i] = 0.f;

    for (int r = 0; r < 5; ++r) {
        const int  row  = h + r - 2;
        const bool rval = (unsigned)row < (unsigned)HH;
        const int  rowc = row < 0 ? 0 : (row > HH - 1 ? HH - 1 : row);
        const int  rb   = rowc * WW;

        // ---- stage: x/y/z/mask halo [w0-4, w0+1027], validity folded ----
        {
            const int s  = tid;
            const int w  = w0 - 4 + s;
            const int wc = w < 0 ? 0 : (w > WW - 1 ? WW - 1 : w);
            const float mv = (rval && (unsigned)w < (unsigned)WW)
                                 ? (float)mb[rb + wc] : 0.f;
            ls_x[s] = xb[0 * hw + rb + wc];
            ls_y[s] = xb[1 * hw + rb + wc];
            ls_z[s] = xb[2 * hw + rb + wc];
            ls_m[s] = mv;
        }
        if (tid < HALO - BPX) {           // 8 tail elements
            const int s  = BPX + tid;
            const int w  = w0 - 4 + s;
            const int wc = w > WW - 1 ? WW - 1 : w;
            const float mv = (rval && (unsigned)w < (unsigned)WW)
                                 ? (float)mb[rb + wc] : 0.f;
            ls_x[s] = xb[0 * hw + rb + wc];
            ls_y[s] = xb[1 * hw + rb + wc];
            ls_z[s] = xb[2 * hw + rb + wc];
            ls_m[s] = mv;
        }
        __syncthreads();                  // barA: stage complete

        // ---- g: 5 taps for pixel pg (computed ONCE, was 4x) ----
        {
            const int gb = (pg >> 2) * GSTR + (pg & 3) * 5;
#pragma unroll
            for (int d = 0; d < 5; ++d) {
                const int s = pg + 2 + d;        // tap w = pcen + d - 2
                const float ax = ls_x[s] - cx;
                const float ay = ls_y[s] - cy;
                const float az = ls_z[s] - cz;
                const float d2 = ax * ax + ay * ay + az * az;
                gq[gb + d] = ls_m[s] * __expf(-0.5f * d2);
            }
        }
        __syncthreads();                  // barB: g complete

        // ---- channel loop: R0-proven body, g from LDS ----
        {
            float g[4][5];
            const int gb = q * GSTR;
#pragma unroll
            for (int i = 0; i < 4; ++i)
#pragma unroll
                for (int d = 0; d < 5; ++d)
                    g[i][d] = gq[gb + i * 5 + d];

#pragma unroll
            for (int c = 0; c < CPT; ++c) {
                const float* sp = smb + (size_t)c * hw + rb;
                const float4 s0 = *(const float4*)(sp + c0);
                const float4 s1 = *(const float4*)(sp + c1);
                const float4 s2 = *(const float4*)(sp + c2);
                const float sw[12] = {s0.x,s0.y,s0.z,s0.w,
                                      s1.x,s1.y,s1.z,s1.w,
                                      s2.x,s2.y,s2.z,s2.w};
#pragma unroll
                for (int i = 0; i < 4; ++i) {
                    float a = acc[c][i];
#pragma unroll
                    for (int d = 0; d < 5; ++d)
                        a = fmaf(g[i][d], sw[i + d + 2], a);
                    acc[c][i] = a;
                }
            }
        }
        // no barrier here: next iteration's barA fences the LDS rewrites
    }

    float* ob = out + (size_t)n * CC * hw + (size_t)((tid >> 8) * CPT) * hw
              + (size_t)h * WW + p0q;
#pragma unroll
    for (int c = 0; c < CPT; ++c)
        *(float4*)(ob + (size_t)c * hw) =
            make_float4(acc[c][0], acc[c][1], acc[c][2], acc[c][3]);
}

extern "C" void kernel_launch(void* const* d_in, const int* in_sizes, int n_in,
                              void* d_out, int out_size, void* d_ws, size_t ws_size,
                              hipStream_t stream) {
    const float* xyz     = (const float*)d_in[0];
    const float* softmax = (const float*)d_in[1];
    const int*   mask    = (const int*)d_in[2];
    float*       out     = (float*)d_out;

    dim3 block(1024, 1, 1);
    dim3 grid(WW / BPX, HH, NN);          // 2 x 64 x 4 = 512 blocks
    hipLaunchKernelGGL(lc_xyz_kernel, grid, block, 0, stream,
                       xyz, softmax, mask, out);
}

// Round 9
// 236.125 us; speedup vs baseline: 1.3712x; 1.3712x over previous
//
#include <hip/hip_runtime.h>

#define NN 4
#define CC 20
#define HH 64
#define WW 2048
#define CG 4           // channel groups
#define CPG (CC / CG)  // 5 channels per group
#define PX 4           // pixels per thread

// R9: h-split dispatch. For h in [2,61] every dy row is valid, so the
// interior kernel runs the 5 R0-proven row bodies STRAIGHT-LINE (no
// branches) — the compiler's list scheduler can then hoist row r+1's
// loads into row r's compute, self-limited by register budget (unlike
// R5's manual RowVec prefetch, which forced live ranges and spilled).
// Edge kernel (h in {0,1,62,63}, 6% of blocks) is exactly R0's branched
// loop. Per-row body is macro-identical in both kernels.
// Tripwire: WRITE_SIZE must stay = pure output (38400/2560 KB), VGPR<=128.

// The proven R0 row body: 3 int4 + 9 float4 window loads, g once per
// (pixel,tap), then CPG channels x 3 float4 + 20 FMA.
#define ROW_BODY(RB)                                                          \
    {                                                                         \
        const int rb = (RB);                                                  \
        const int4 m0 = *(const int4*)(mb + rb + c0);                         \
        const int4 m1 = *(const int4*)(mb + rb + c1);                         \
        const int4 m2 = *(const int4*)(mb + rb + c2);                         \
        const float4 x0 = *(const float4*)(xb + 0 * hw + rb + c0);            \
        const float4 x1 = *(const float4*)(xb + 0 * hw + rb + c1);            \
        const float4 x2 = *(const float4*)(xb + 0 * hw + rb + c2);            \
        const float4 y0 = *(const float4*)(xb + 1 * hw + rb + c0);            \
        const float4 y1 = *(const float4*)(xb + 1 * hw + rb + c1);            \
        const float4 y2 = *(const float4*)(xb + 1 * hw + rb + c2);            \
        const float4 z0 = *(const float4*)(xb + 2 * hw + rb + c0);            \
        const float4 z1 = *(const float4*)(xb + 2 * hw + rb + c1);            \
        const float4 z2 = *(const float4*)(xb + 2 * hw + rb + c2);            \
        const float xw[12] = {x0.x,x0.y,x0.z,x0.w, x1.x,x1.y,x1.z,x1.w,       \
                              x2.x,x2.y,x2.z,x2.w};                           \
        const float yw[12] = {y0.x,y0.y,y0.z,y0.w, y1.x,y1.y,y1.z,y1.w,       \
                              y2.x,y2.y,y2.z,y2.w};                           \
        const float zw[12] = {z0.x,z0.y,z0.z,z0.w, z1.x,z1.y,z1.z,z1.w,       \
                              z2.x,z2.y,z2.z,z2.w};                           \
        const int   mi[12] = {m0.x,m0.y,m0.z,m0.w, m1.x,m1.y,m1.z,m1.w,       \
                              m2.x,m2.y,m2.z,m2.w};                           \
        float mf[12];                                                         \
        _Pragma("unroll")                                                     \
        for (int j = 2; j <= 9; ++j) mf[j] = vf[j] * (float)mi[j];            \
        float g[PX][5];                                                       \
        _Pragma("unroll")                                                     \
        for (int i = 0; i < PX; ++i) {                                        \
            _Pragma("unroll")                                                 \
            for (int dx = 0; dx < 5; ++dx) {                                  \
                const int j = i + dx + 2;                                     \
                const float ax = xw[j] - cx[i];                               \
                const float ay = yw[j] - cy[i];                               \
                const float az = zw[j] - cz[i];                               \
                const float d2 = ax * ax + ay * ay + az * az;                 \
                g[i][dx] = mf[j] * __expf(-0.5f * d2);                        \
            }                                                                 \
        }                                                                     \
        _Pragma("unroll")                                                     \
        for (int c = 0; c < CPG; ++c) {                                       \
            const float* sp = smb + (size_t)c * hw + rb;                      \
            const float4 s0 = *(const float4*)(sp + c0);                      \
            const float4 s1 = *(const float4*)(sp + c1);                      \
            const float4 s2 = *(const float4*)(sp + c2);                      \
            const float sw[12] = {s0.x,s0.y,s0.z,s0.w, s1.x,s1.y,s1.z,s1.w,   \
                                  s2.x,s2.y,s2.z,s2.w};                       \
            _Pragma("unroll")                                                 \
            for (int i = 0; i < PX; ++i) {                                    \
                float a = acc[c][i];                                          \
                _Pragma("unroll")                                             \
                for (int dx = 0; dx < 5; ++dx)                                \
                    a = fmaf(g[i][dx], sw[i + dx + 2], a);                    \
                acc[c][i] = a;                                                \
            }                                                                 \
        }                                                                     \
    }

#define COMMON_SETUP                                                          \
    const int t  = blockIdx.x * blockDim.x + threadIdx.x;                     \
    const int nz = blockIdx.z;                                                \
    const int n  = nz >> 2;                                                   \
    const int cg = nz & 3;                                                    \
    const int hw = HH * WW;                                                   \
    const int p0 = t * PX;                                                    \
    const float* xb  = xyz     + (size_t)n * 3  * hw;                         \
    const float* smb = softmax + (size_t)n * CC * hw + (size_t)(cg * CPG) * hw; \
    const int*   mb  = mask    + (size_t)n * hw;                              \
    const int ctr = h * WW + p0;                                              \
    const float4 cxv = *(const float4*)(xb + 0 * hw + ctr);                   \
    const float4 cyv = *(const float4*)(xb + 1 * hw + ctr);                   \
    const float4 czv = *(const float4*)(xb + 2 * hw + ctr);                   \
    const float cx[PX] = {cxv.x, cxv.y, cxv.z, cxv.w};                        \
    const float cy[PX] = {cyv.x, cyv.y, cyv.z, cyv.w};                        \
    const float cz[PX] = {czv.x, czv.y, czv.z, czv.w};                        \
    float acc[CPG][PX];                                                       \
    _Pragma("unroll")                                                         \
    for (int c = 0; c < CPG; ++c)                                             \
        _Pragma("unroll")                                                     \
        for (int i = 0; i < PX; ++i) acc[c][i] = 0.f;                         \
    int c0 = p0 - 4; if (c0 < 0) c0 = 0;                                      \
    const int c1 = p0;                                                        \
    int c2 = p0 + 4; if (c2 > WW - 4) c2 = WW - 4;                            \
    float vf[12];                                                             \
    _Pragma("unroll")                                                         \
    for (int j = 2; j <= 9; ++j)                                              \
        vf[j] = ((unsigned)(p0 - 4 + j) < (unsigned)WW) ? 1.f : 0.f;

#define WRITE_OUT                                                             \
    float* ob = out + (size_t)n * CC * hw + (size_t)(cg * CPG) * hw + ctr;    \
    _Pragma("unroll")                                                         \
    for (int c = 0; c < CPG; ++c)                                             \
        *(float4*)(ob + (size_t)c * hw) =                                     \
            make_float4(acc[c][0], acc[c][1], acc[c][2], acc[c][3]);

// Interior: h in [2,61] — all 5 tap rows valid, straight-line bodies.
__global__ __launch_bounds__(256, 4) void lc_xyz_interior(
    const float* __restrict__ xyz,
    const float* __restrict__ softmax,
    const int* __restrict__ mask,
    float* __restrict__ out)
{
    const int h = (int)blockIdx.y + 2;
    COMMON_SETUP
    const int rb0 = (h - 2) * WW;
    ROW_BODY(rb0)
    ROW_BODY(rb0 + WW)
    ROW_BODY(rb0 + 2 * WW)
    ROW_BODY(rb0 + 3 * WW)
    ROW_BODY(rb0 + 4 * WW)
    WRITE_OUT
}

// Edge: h in {0,1,62,63} — exact R0 branched loop.
__global__ __launch_bounds__(256, 4) void lc_xyz_edge(
    const float* __restrict__ xyz,
    const float* __restrict__ softmax,
    const int* __restrict__ mask,
    float* __restrict__ out)
{
    const int y = (int)blockIdx.y;            // 0..3
    const int h = (y < 2) ? y : (y + 60);     // {0,1,62,63}
    COMMON_SETUP
#pragma unroll
    for (int dy = -2; dy <= 2; ++dy) {
        const int row = h + dy;
        if ((unsigned)row >= (unsigned)HH) continue;   // wave-uniform
        ROW_BODY(row * WW)
    }
    WRITE_OUT
}

extern "C" void kernel_launch(void* const* d_in, const int* in_sizes, int n_in,
                              void* d_out, int out_size, void* d_ws, size_t ws_size,
                              hipStream_t stream) {
    const float* xyz     = (const float*)d_in[0];
    const float* softmax = (const float*)d_in[1];
    const int*   mask    = (const int*)d_in[2];
    float*       out     = (float*)d_out;

    dim3 block(256, 1, 1);
    dim3 gridI(WW / (PX * 256), HH - 4, NN * CG);  // 2 x 60 x 16 = 1920 blocks
    dim3 gridE(WW / (PX * 256), 4,      NN * CG);  // 2 x  4 x 16 =  128 blocks
    hipLaunchKernelGGL(lc_xyz_interior, gridI, block, 0, stream,
                       xyz, softmax, mask, out);
    hipLaunchKernelGGL(lc_xyz_edge, gridE, block, 0, stream,
                       xyz, softmax, mask, out);
}

// Round 10
// 197.554 us; speedup vs baseline: 1.6389x; 1.1952x over previous
//
#include <hip/hip_runtime.h>

#define NN 4
#define CC 20
#define HH 64
#define WW 2048
#define CG 4           // channel groups
#define CPG (CC / CG)  // 5 channels per group
#define PX 4           // pixels per thread

// EXACT R0 body — the unique spill-free shape (six restructuring attempts
// R1/R3/R5/R7/R8/R9 all hit the scratch cliff). ONE change vs R0:
// __launch_bounds__(256,4) -> (256,6). VGPR budget 512/6 = 85 > the
// kernel's natural 64, so allocation is unchanged, but residency rises
// from 4 to 6 blocks/CU (16 -> 24 waves/CU) for this latency-bound body
// (all pipes <=40% at 34% occupancy). R3's (256,8) was confounded: its
// 64-VGPR cap forced a 32-VGPR allocation and catastrophic spill.
// Tripwires: VGPR must stay ~60-64, WRITE_SIZE must stay 40960 KB.
__global__ __launch_bounds__(256, 6) void lc_xyz_kernel(
    const float* __restrict__ xyz,
    const float* __restrict__ softmax,
    const int* __restrict__ mask,
    float* __restrict__ out)
{
    const int t  = blockIdx.x * blockDim.x + threadIdx.x;  // pixel-quad index in row
    const int h  = blockIdx.y;
    const int nz = blockIdx.z;
    const int n  = nz >> 2;
    const int cg = nz & 3;
    const int hw = HH * WW;
    const int p0 = t * PX;

    const float* xb  = xyz     + (size_t)n * 3  * hw;
    const float* smb = softmax + (size_t)n * CC * hw + (size_t)(cg * CPG) * hw;
    const int*   mb  = mask    + (size_t)n * hw;

    const int ctr = h * WW + p0;
    const float4 cxv = *(const float4*)(xb + 0 * hw + ctr);
    const float4 cyv = *(const float4*)(xb + 1 * hw + ctr);
    const float4 czv = *(const float4*)(xb + 2 * hw + ctr);
    const float cx[PX] = {cxv.x, cxv.y, cxv.z, cxv.w};
    const float cy[PX] = {cyv.x, cyv.y, cyv.z, cyv.w};
    const float cz[PX] = {czv.x, czv.y, czv.z, czv.w};

    float acc[CPG][PX];
#pragma unroll
    for (int c = 0; c < CPG; ++c)
#pragma unroll
        for (int i = 0; i < PX; ++i) acc[c][i] = 0.f;

    // Window indices j=0..11 map to w = p0-4+j; taps use j = i+dx+2 in [2,9].
    // Aligned 16B chunks at p0-4, p0, p0+4; edge chunks clamped (their taps
    // are zeroed via validity, and all VALID taps come from unclamped chunks).
    int c0 = p0 - 4; if (c0 < 0) c0 = 0;
    const int c1 = p0;
    int c2 = p0 + 4; if (c2 > WW - 4) c2 = WW - 4;

    float vf[12];
#pragma unroll
    for (int j = 2; j <= 9; ++j)
        vf[j] = ((unsigned)(p0 - 4 + j) < (unsigned)WW) ? 1.f : 0.f;

#pragma unroll
    for (int dy = -2; dy <= 2; ++dy) {
        const int row = h + dy;
        if ((unsigned)row >= (unsigned)HH) continue;   // wave-uniform
        const int rb = row * WW;

        // Batched independent row loads: 3 int4 + 9 float4.
        const int4 m0 = *(const int4*)(mb + rb + c0);
        const int4 m1 = *(const int4*)(mb + rb + c1);
        const int4 m2 = *(const int4*)(mb + rb + c2);
        const float4 x0 = *(const float4*)(xb + 0 * hw + rb + c0);
        const float4 x1 = *(const float4*)(xb + 0 * hw + rb + c1);
        const float4 x2 = *(const float4*)(xb + 0 * hw + rb + c2);
        const float4 y0 = *(const float4*)(xb + 1 * hw + rb + c0);
        const float4 y1 = *(const float4*)(xb + 1 * hw + rb + c1);
        const float4 y2 = *(const float4*)(xb + 1 * hw + rb + c2);
        const float4 z0 = *(const float4*)(xb + 2 * hw + rb + c0);
        const float4 z1 = *(const float4*)(xb + 2 * hw + rb + c1);
        const float4 z2 = *(const float4*)(xb + 2 * hw + rb + c2);

        const float xw[12] = {x0.x,x0.y,x0.z,x0.w, x1.x,x1.y,x1.z,x1.w, x2.x,x2.y,x2.z,x2.w};
        const float yw[12] = {y0.x,y0.y,y0.z,y0.w, y1.x,y1.y,y1.z,y1.w, y2.x,y2.y,y2.z,y2.w};
        const float zw[12] = {z0.x,z0.y,z0.z,z0.w, z1.x,z1.y,z1.z,z1.w, z2.x,z2.y,z2.z,z2.w};
        const int   mi[12] = {m0.x,m0.y,m0.z,m0.w, m1.x,m1.y,m1.z,m1.w, m2.x,m2.y,m2.z,m2.w};

        float mf[12];
#pragma unroll
        for (int j = 2; j <= 9; ++j) mf[j] = vf[j] * (float)mi[j];

        // Gaussian weights, once per (pixel, tap), shared across channels.
        float g[PX][5];
#pragma unroll
        for (int i = 0; i < PX; ++i) {
#pragma unroll
            for (int dx = 0; dx < 5; ++dx) {
                const int j = i + dx + 2;
                const float ax = xw[j] - cx[i];
                const float ay = yw[j] - cy[i];
                const float az = zw[j] - cz[i];
                const float d2 = ax * ax + ay * ay + az * az;
                g[i][dx] = mf[j] * __expf(-0.5f * d2);
            }
        }

        // Channel loop: 3 float4 loads + 20 FMA per channel.
#pragma unroll
        for (int c = 0; c < CPG; ++c) {
            const float* sp = smb + (size_t)c * hw + rb;
            const float4 s0 = *(const float4*)(sp + c0);
            const float4 s1 = *(const float4*)(sp + c1);
            const float4 s2 = *(const float4*)(sp + c2);
            const float sw[12] = {s0.x,s0.y,s0.z,s0.w, s1.x,s1.y,s1.z,s1.w, s2.x,s2.y,s2.z,s2.w};
#pragma unroll
            for (int i = 0; i < PX; ++i) {
                float a = acc[c][i];
#pragma unroll
                for (int dx = 0; dx < 5; ++dx)
                    a = fmaf(g[i][dx], sw[i + dx + 2], a);
                acc[c][i] = a;
            }
        }
    }

    float* ob = out + (size_t)n * CC * hw + (size_t)(cg * CPG) * hw + ctr;
#pragma unroll
    for (int c = 0; c < CPG; ++c)
        *(float4*)(ob + (size_t)c * hw) =
            make_float4(acc[c][0], acc[c][1], acc[c][2], acc[c][3]);
}

extern "C" void kernel_launch(void* const* d_in, const int* in_sizes, int n_in,
                              void* d_out, int out_size, void* d_ws, size_t ws_size,
                              hipStream_t stream) {
    const float* xyz     = (const float*)d_in[0];
    const float* softmax = (const float*)d_in[1];
    const int*   mask    = (const int*)d_in[2];
    float*       out     = (float*)d_out;

    dim3 block(256, 1, 1);
    dim3 grid(WW / (PX * 256), HH, NN * CG);   // 2 x 64 x 16 = 2048 blocks
    hipLaunchKernelGGL(lc_xyz_kernel, grid, block, 0, stream,
                       xyz, softmax, mask, out);
}